// Round 13
// baseline (83.160 us; speedup 1.0000x reference)
//
#include <hip/hip_runtime.h>
#include <math.h>

// ---------------------------------------------------------------------------
// LorentzSelfAttention — MI355X
//
// Degenerate-clamp simplification (verified analytically, passed R1-R12):
//   u_agg_i = C*(W_i + S_i*Q_i),  W_i = sum_j p_ij V_j (unnormalized),
//   S_i = sum_j p_ij alpha_ij,  p_ij = exp(-d^2)*dist_ij
//   Y_i = mink_normalize(Q_i + u_agg_i/sum_e), |time|
//   Ztan_i = dist0*C * (2*Y0, Ys),  dist0 = acosh(max(Y0,1+eps))
//
// R13: consolidation round for attribution. QKV path collapsed to ONE kernel:
// 16x64-tile GEMM (grid 12x64 = 768 blocks, 3/CU — same parallelism as
// split-K x2 but NO zpart round-trip, NO reduce_fl dispatch, fused FL lift).
// attn + out_gemm verbatim from R8 (best measured, 79.9). 3 dispatches total.
// If total doesn't move, the ~20us hole is attn stalls -> MFMA rewrite next.
// ---------------------------------------------------------------------------

namespace {

constexpr int Tq = 512;
constexpr int QS = 36;            // padded Q row stride

#define EPSF  1e-6f
#define CINV  3.16227766e7f       // 1/sqrt(1e-15)

__device__ __forceinline__ float facosh(float x) {
    // caller guarantees x >= 1+1e-6
    return __logf(x + __builtin_amdgcn_sqrtf(fmaf(x, x, -1.0f)));
}

// ---------------- Kernel 1: QKV GEMM 16x64 + fused bias + FL lift ----------
// grid (12, 64): n0 = bx*64 (output col block), m0 = by*16 (row block).
__global__ __launch_bounds__(256) void gemm_qkv_fl_kernel(
    const float* __restrict__ x,
    const float* __restrict__ Wq, const float* __restrict__ bq,
    const float* __restrict__ Wk, const float* __restrict__ bk,
    const float* __restrict__ Wv, const float* __restrict__ bv,
    float* __restrict__ Q, float* __restrict__ K, float* __restrict__ V)
{
    __shared__ float AsT[32][17];     // k-major A tile (16 rows)
    __shared__ float BsT[32][68];     // k-major B tile (64 cols)
    __shared__ float sT[16][65];      // epilogue z-tile

    const int n0 = blockIdx.x * 64;   // 0..704
    const int m0 = blockIdx.y * 16;   // 0..1008
    const int t  = threadIdx.x;
    const int tx = t & 15, ty = t >> 4;

    float acc[4] = {0.f, 0.f, 0.f, 0.f};

    // staging indices
    const int ar  = t >> 4;           // A row 0..15
    const int ac2 = (t & 15) * 2;     // A k 0..30
    const int br  = t >> 2;           // B col 0..63
    const int bc  = (t & 3) * 8;      // B k 0,8,16,24
    const int ob  = n0 + br;
    const float* WselB = (ob < 256) ? Wq : (ob < 512 ? Wk : Wv);
    const int obr = ob & 255;

    for (int k0 = 0; k0 < 512; k0 += 32) {
        const float2 a2 = *reinterpret_cast<const float2*>(&x[(m0 + ar) * 512 + k0 + ac2]);
        AsT[ac2][ar] = a2.x; AsT[ac2 + 1][ar] = a2.y;
        const float4 b0 = *reinterpret_cast<const float4*>(&WselB[obr * 512 + k0 + bc]);
        const float4 b1 = *reinterpret_cast<const float4*>(&WselB[obr * 512 + k0 + bc + 4]);
        BsT[bc + 0][br] = b0.x; BsT[bc + 1][br] = b0.y;
        BsT[bc + 2][br] = b0.z; BsT[bc + 3][br] = b0.w;
        BsT[bc + 4][br] = b1.x; BsT[bc + 5][br] = b1.y;
        BsT[bc + 6][br] = b1.z; BsT[bc + 7][br] = b1.w;
        __syncthreads();
        #pragma unroll
        for (int kk = 0; kk < 32; ++kk) {
            const float a = AsT[kk][ty];
            const float4 b4 = *reinterpret_cast<const float4*>(&BsT[kk][tx * 4]);
            acc[0] = fmaf(a, b4.x, acc[0]);
            acc[1] = fmaf(a, b4.y, acc[1]);
            acc[2] = fmaf(a, b4.z, acc[2]);
            acc[3] = fmaf(a, b4.w, acc[3]);
        }
        __syncthreads();
    }

    #pragma unroll
    for (int c = 0; c < 4; ++c) {
        const int o = n0 + tx * 4 + c;
        const float* bsel = (o < 256) ? bq : (o < 512 ? bk : bv);
        sT[ty][tx * 4 + c] = acc[c] + bsel[o & 255];
    }
    __syncthreads();

    // FL lift: 32 threads, one (row, head-half) each
    if (t < 32) {
        const int m = t >> 1, half = t & 1;
        const int row = m0 + m;
        const int b = row >> 9, tt = row & 511;
        const int which = n0 >> 8;           // 0=q 1=k 2=v
        const int h = ((n0 & 255) >> 5) + half;
        const int bh = b * 8 + h;

        float zv[32];
        float s2 = 0.f;
        #pragma unroll
        for (int k = 0; k < 32; ++k) { zv[k] = sT[m][half * 32 + k]; s2 = fmaf(zv[k], zv[k], s2); }
        const float rr = __builtin_amdgcn_sqrtf(s2);
        const float rs = fminf(fmaxf(rr, 1e-12f), 18.0f);
        const float e  = __expf(rs);
        const float ei = __builtin_amdgcn_rcpf(e);
        const float ch = 0.5f * (e + ei);
        float sc = 0.5f * (e - ei) / rs;
        if (rs < 1e-3f) sc = fmaf(rs * rs, 1.0f / 6.0f, 1.0f);
        float y0 = ch;
        float ys[32];
        float mink = -y0 * y0;
        #pragma unroll
        for (int k = 0; k < 32; ++k) { ys[k] = sc * zv[k]; mink = fmaf(ys[k], ys[k], mink); }
        const float inv = __builtin_amdgcn_rsqf(fmaxf(fabsf(mink), 1e-15f));
        y0 = fabsf(y0 * inv);

        if (which == 0) {
            float* qp = Q + (bh * Tq + tt) * QS;
            #pragma unroll
            for (int k = 0; k < 32; ++k) qp[k] = ys[k] * inv;
            qp[32] = y0; qp[33] = 0.f; qp[34] = 0.f; qp[35] = 0.f;
        } else {
            float* p = ((which == 1) ? K : V) + bh * 33 * Tq + tt;
            p[0] = y0;
            #pragma unroll
            for (int k = 0; k < 32; ++k) p[(k + 1) * Tq] = ys[k] * inv;
        }
    }
}

// ---------------- Kernel 2: attention (R8 verbatim) ------------------------
// 256 threads, 8 rows/block, 2 columns/thread, grid (64, 16).
__global__ __launch_bounds__(256) void attn_kernel(
    const float* __restrict__ Q, const float* __restrict__ K,
    const float* __restrict__ V, float* __restrict__ Ztan)
{
    __shared__ float sQ[8][36];       // [0..31]=spatial, [32]=time, 33-35 pad
    __shared__ float sBig[8 * 512];   // p matrix; P4 partials alias front
    __shared__ float sSe[8][4];       // per-wave sum_e partials
    __shared__ float sSa[8][4];       // per-wave sum_(p*al) partials
    __shared__ float sW[8][33];

    float (*sP)[512] = reinterpret_cast<float(*)[512]>(sBig);
    float (*part)[8][36] = reinterpret_cast<float(*)[8][36]>(sBig); // [g][sub][36]

    const int bh = blockIdx.y;
    const int i0 = blockIdx.x * 8;
    const int t  = threadIdx.x;       // 0..255
    const int lane = t & 63, wv = t >> 6;

    const float* Qb = Q + (bh * Tq + i0) * QS;
    const float* Kb = K + bh * 33 * Tq;
    const float* Vb = V + bh * 33 * Tq;

    for (int idx = t; idx < 8 * QS; idx += 256)
        sQ[idx / QS][idx % QS] = Qb[idx];
    __syncthreads();

    // ---- P1: p = exp(-d^2)*dd into LDS; row sums of e and p*al in regs ----
    float se[8], sa[8];
    #pragma unroll
    for (int i = 0; i < 8; ++i) { se[i] = 0.f; sa[i] = 0.f; }

    #pragma unroll 1
    for (int cc = 0; cc < 2; ++cc) {
        const int j = (cc << 8) + t;
        float aK[8], aV[8];
        #pragma unroll
        for (int i = 0; i < 8; ++i) { aK[i] = 0.f; aV[i] = 0.f; }
        #pragma unroll 2
        for (int ch = 0; ch < 4; ++ch) {
            float ks[8], vs[8];
            #pragma unroll
            for (int k = 0; k < 8; ++k) {
                ks[k] = Kb[(ch * 8 + k + 1) * Tq + j];
                vs[k] = Vb[(ch * 8 + k + 1) * Tq + j];
            }
            #pragma unroll
            for (int i = 0; i < 8; ++i) {
                const float4 qa = *reinterpret_cast<const float4*>(&sQ[i][ch * 8]);
                const float4 qb = *reinterpret_cast<const float4*>(&sQ[i][ch * 8 + 4]);
                float sK = aK[i], sV = aV[i];
                sK = fmaf(qa.x, ks[0], sK); sK = fmaf(qa.y, ks[1], sK);
                sK = fmaf(qa.z, ks[2], sK); sK = fmaf(qa.w, ks[3], sK);
                sK = fmaf(qb.x, ks[4], sK); sK = fmaf(qb.y, ks[5], sK);
                sK = fmaf(qb.z, ks[6], sK); sK = fmaf(qb.w, ks[7], sK);
                sV = fmaf(qa.x, vs[0], sV); sV = fmaf(qa.y, vs[1], sV);
                sV = fmaf(qa.z, vs[2], sV); sV = fmaf(qa.w, vs[3], sV);
                sV = fmaf(qb.x, vs[4], sV); sV = fmaf(qb.y, vs[5], sV);
                sV = fmaf(qb.z, vs[6], sV); sV = fmaf(qb.w, vs[7], sV);
                aK[i] = sK; aV[i] = sV;
            }
        }
        const float k0v = Kb[j], v0v = Vb[j];
        #pragma unroll
        for (int i = 0; i < 8; ++i) {
            const float q0 = sQ[i][32];
            const float ipK = fmaf(q0, k0v, -aK[i]);
            const float d   = facosh(fmaxf(ipK, 1.0f + EPSF));
            const float al  = fmaxf(fmaf(q0, v0v, -aV[i]), 1.0f + EPSF);
            const float dd  = facosh(al);
            const float e   = __expf(-d * d);
            const float p   = e * dd;
            sP[i][j] = p;
            se[i] += e;
            sa[i]  = fmaf(p, al, sa[i]);
        }
    }
    #pragma unroll
    for (int i = 0; i < 8; ++i) {
        float a = se[i], b = sa[i];
        #pragma unroll
        for (int off = 32; off > 0; off >>= 1) {
            a += __shfl_xor(a, off, 64);
            b += __shfl_xor(b, off, 64);
        }
        if (lane == 0) { sSe[i][wv] = a; sSa[i][wv] = b; }
    }
    __syncthreads();

    // ---- P4: Wraw[i][a] = sum_j p_ij * V[a][j] ----------------------------
    {
        const int jl = t & 31, g = t >> 5;
        const int rg = g & 1, ag = g >> 1;
        const int abase = ag * 8;         // 0,8,16,24; +8 = 32 in range
        const int ibase = rg * 4;
        float acc[4][9];
        #pragma unroll
        for (int il = 0; il < 4; ++il)
            #pragma unroll
            for (int al = 0; al < 9; ++al) acc[il][al] = 0.f;

        #pragma unroll 1
        for (int it = 0; it < 8; ++it) {
            const int jb = it * 64 + jl * 2;
            float2 v2[9];
            #pragma unroll
            for (int al = 0; al < 9; ++al)
                v2[al] = *reinterpret_cast<const float2*>(&Vb[(abase + al) * Tq + jb]);
            #pragma unroll
            for (int il = 0; il < 4; ++il) {
                const float2 w2 = *reinterpret_cast<const float2*>(&sP[ibase + il][jb]);
                #pragma unroll
                for (int al = 0; al < 9; ++al)
                    acc[il][al] = fmaf(w2.y, v2[al].y, fmaf(w2.x, v2[al].x, acc[il][al]));
            }
        }
        #pragma unroll
        for (int il = 0; il < 4; ++il)
            #pragma unroll
            for (int al = 0; al < 9; ++al) {
                float v = acc[il][al];
                v += __shfl_xor(v, 1, 64);
                v += __shfl_xor(v, 2, 64);
                acc[il][al] = v;
            }
        __syncthreads();   // all sP reads complete before part overwrites
        if ((jl & 3) == 0) {
            const int sub = jl >> 2;
            #pragma unroll
            for (int il = 0; il < 4; ++il)
                #pragma unroll
                for (int al = 0; al < 9; ++al)
                    part[g][sub][il * 9 + al] = acc[il][al];
        }
    }
    __syncthreads();

    // ---- stage 2: fold 8 partials per (i,a) -------------------------------
    for (int task = t; task < 8 * 33; task += 256) {
        const int i = task / 33, a = task - i * 33;
        int ag2 = a >> 3; if (ag2 > 3) ag2 = 3;
        const int al = a - ag2 * 8;
        const int g2 = ag2 * 2 + (i >> 2);
        const int idx = (i & 3) * 9 + al;
        float s = 0.f;
        #pragma unroll
        for (int sub = 0; sub < 8; ++sub) s += part[g2][sub][idx];
        sW[i][a] = s;
    }
    __syncthreads();

    // ---- P5: normalize + degenerate exp_map + project + origin log --------
    if (t < 8) {
        const int i = t;
        const float seT = sSe[i][0] + sSe[i][1] + sSe[i][2] + sSe[i][3];
        const float saT = sSa[i][0] + sSa[i][1] + sSa[i][2] + sSa[i][3];
        const float sInv = __builtin_amdgcn_rcpf(seT);
        const float cs = CINV * sInv;     // C * (1/sum_e)
        const float q0 = sQ[i][32];
        const float y0 = fmaf(cs, fmaf(saT, q0, sW[i][0]), q0);
        float mink = -y0 * y0;
        float yv[32];
        #pragma unroll
        for (int a = 1; a < 33; ++a) {
            const float qa = sQ[i][a - 1];
            const float ya = fmaf(cs, fmaf(saT, qa, sW[i][a]), qa);
            yv[a - 1] = ya;
            mink = fmaf(ya, ya, mink);
        }
        const float inv = __builtin_amdgcn_rsqf(fmaxf(fabsf(mink), 1e-15f));
        const float Y0 = fabsf(y0 * inv);
        const float dist0 = facosh(fmaxf(Y0, 1.0f + EPSF));
        const float coef = dist0 * CINV;
        const int b = bh >> 3, h = bh & 7;
        float* zp = Ztan + ((b * Tq + (i0 + i)) * 264) + h * 33;
        zp[0] = coef * (2.0f * Y0);
        #pragma unroll
        for (int a = 1; a < 33; ++a) zp[a] = coef * (yv[a - 1] * inv);
    }
}

// ---------------- Kernel 3: Z = Ztan(1024x264) @ Wo^T + bo, 32x32 (R8) -----
__global__ __launch_bounds__(256) void out_gemm_kernel(
    const float* __restrict__ Ztan, const float* __restrict__ Wo,
    const float* __restrict__ bo, float* __restrict__ out)
{
    __shared__ float AsT[8][36];
    __shared__ float BsT[8][36];
    const int n0 = blockIdx.x * 32;
    const int m0 = blockIdx.y * 32;
    const int t  = threadIdx.x;
    const int tx = t & 15, ty = t >> 4;
    const int ar = t >> 3, ac = t & 7;

    float acc[2][2];
    acc[0][0] = acc[0][1] = acc[1][0] = acc[1][1] = 0.f;

    for (int k0 = 0; k0 < 264; k0 += 8) {
        AsT[ac][ar] = Ztan[(m0 + ar) * 264 + k0 + ac];
        BsT[ac][ar] = Wo[(n0 + ar) * 264 + k0 + ac];
        __syncthreads();
        #pragma unroll
        for (int kk = 0; kk < 8; ++kk) {
            const float2 a2 = *reinterpret_cast<const float2*>(&AsT[kk][ty * 2]);
            const float2 b2 = *reinterpret_cast<const float2*>(&BsT[kk][tx * 2]);
            acc[0][0] = fmaf(a2.x, b2.x, acc[0][0]);
            acc[0][1] = fmaf(a2.x, b2.y, acc[0][1]);
            acc[1][0] = fmaf(a2.y, b2.x, acc[1][0]);
            acc[1][1] = fmaf(a2.y, b2.y, acc[1][1]);
        }
        __syncthreads();
    }
    #pragma unroll
    for (int c = 0; c < 2; ++c) {
        const int o = n0 + tx * 2 + c;
        const float bias = bo[o];
        #pragma unroll
        for (int r = 0; r < 2; ++r)
            out[(m0 + ty * 2 + r) * 512 + o] = acc[r][c] + bias;
    }
}

} // namespace

// ---------------------------------------------------------------------------
extern "C" void kernel_launch(void* const* d_in, const int* in_sizes, int n_in,
                              void* d_out, int out_size, void* d_ws, size_t ws_size,
                              hipStream_t stream)
{
    const float* x  = (const float*)d_in[0];
    const float* Wq = (const float*)d_in[1];
    const float* bq = (const float*)d_in[2];
    const float* Wk = (const float*)d_in[3];
    const float* bk = (const float*)d_in[4];
    const float* Wv = (const float*)d_in[5];
    const float* bv = (const float*)d_in[6];
    const float* Wo = (const float*)d_in[7];
    const float* bo = (const float*)d_in[8];
    float* out = (float*)d_out;

    float* ws  = (float*)d_ws;
    float* Qw  = ws;                          // 294912
    float* Kw  = Qw + 294912;                 // 272384 (33 rows + pad)
    float* Vw  = Kw + 272384;                 // 272384
    float* Zt  = Vw + 272384;                 // 270336

    gemm_qkv_fl_kernel<<<dim3(12, 64), 256, 0, stream>>>(x, Wq, bq, Wk, bk, Wv, bv,
                                                         Qw, Kw, Vw);
    attn_kernel<<<dim3(64, 16), 256, 0, stream>>>(Qw, Kw, Vw, Zt);
    out_gemm_kernel<<<dim3(16, 32), 256, 0, stream>>>(Zt, Wo, bo, out);
}

// Round 14
// 68.967 us; speedup vs baseline: 1.2058x; 1.2058x over previous
//
#include <hip/hip_runtime.h>
#include <math.h>

// ---------------------------------------------------------------------------
// LorentzSelfAttention — MI355X
//
// Degenerate-clamp simplification (verified analytically, passed R1-R13):
//   u_agg_i = C*(W_i + S_i*Q_i),  W_i = sum_j p_ij V_j,  p = exp(-d^2)*dist
//   Y_i = mink_normalize(Q_i + u_agg_i/sum_e), |time|
//   Ztan_i = dist0*C * (2*Y0, Ys)
//
// R14: QKV GEMM rewritten with MFMA (bf16 hi/lo split: z = xh*Wh + xh*Wl +
// xl*Wh, truncation split -> ~2^-16 rel err, negligible). Diagnosis: the f32
// SMEM GEMM was LDS-bandwidth-bound (~25us: 1.25KB LDS per 16 FMA at
// 128B/clk/CU); f32 VALU floor is 8us; MFMA makes it staging-bound ~4us.
// 64x64 tile, 4 waves (2x2 of 32x32 each = 2x2 of 16x16x32 mfma), BK=64,
// fused bias+FL epilogue (R6-verified). attn + out_gemm R8-verbatim.
// ---------------------------------------------------------------------------

namespace {

constexpr int Tq = 512;
constexpr int QS = 36;            // padded Q row stride

#define EPSF  1e-6f
#define CINV  3.16227766e7f       // 1/sqrt(1e-15)

using short8 = __attribute__((ext_vector_type(8))) short;
using f32x4  = __attribute__((ext_vector_type(4))) float;

__device__ __forceinline__ float facosh(float x) {
    return __logf(x + __builtin_amdgcn_sqrtf(fmaf(x, x, -1.0f)));
}

__device__ __forceinline__ void cvt_hilo(float x, unsigned short& h, unsigned short& l) {
    const unsigned u = __float_as_uint(x);
    h = (unsigned short)(u >> 16);
    const float xh = __uint_as_float(u & 0xFFFF0000u);
    l = (unsigned short)(__float_as_uint(x - xh) >> 16);
}

__device__ __forceinline__ uint4 pack8(const unsigned short* s) {
    uint4 r;
    r.x = (unsigned)s[0] | ((unsigned)s[1] << 16);
    r.y = (unsigned)s[2] | ((unsigned)s[3] << 16);
    r.z = (unsigned)s[4] | ((unsigned)s[5] << 16);
    r.w = (unsigned)s[6] | ((unsigned)s[7] << 16);
    return r;
}

// ---------------- Kernel 1: QKV GEMM via MFMA (hi/lo bf16) + bias + FL -----
// grid (12, 16): n0 = bx*64 (feature block = 2 heads of q/k/v), m0 = by*64.
__global__ __launch_bounds__(256) void gemm_qkv_mfma_kernel(
    const float* __restrict__ x,
    const float* __restrict__ Wq, const float* __restrict__ bq,
    const float* __restrict__ Wk, const float* __restrict__ bk,
    const float* __restrict__ Wv, const float* __restrict__ bv,
    float* __restrict__ Q, float* __restrict__ K, float* __restrict__ V)
{
    __shared__ unsigned short Ah[64][72], Al[64][72];   // bf16 hi/lo, [row][k]
    __shared__ unsigned short Bh[64][72], Bl[64][72];   // [feature][k]
    __shared__ float sT[64][65];

    const int n0 = blockIdx.x * 64;
    const int m0 = blockIdx.y * 64;
    const int t  = threadIdx.x;
    const int l  = t & 63, w = t >> 6;
    const int wr = (w >> 1) * 32, wc = (w & 1) * 32;    // wave tile origin
    const int fr = l & 15, fk = (l >> 4) * 8;           // fragment indices

    // staging indices: thread covers one 16-wide k-segment of one row
    const int sr  = t >> 2;           // 0..63
    const int seg = (t & 3) * 16;     // 0,16,32,48
    const int ob  = n0 + sr;
    const float* WselB = (ob < 256) ? Wq : (ob < 512 ? Wk : Wv);
    const int obr = ob & 255;

    f32x4 acc[2][2];
    #pragma unroll
    for (int mt = 0; mt < 2; ++mt)
        #pragma unroll
        for (int nt = 0; nt < 2; ++nt) acc[mt][nt] = (f32x4){0.f, 0.f, 0.f, 0.f};

    for (int k0 = 0; k0 < 512; k0 += 64) {
        // ---- stage A (x) and B (W) as bf16 hi/lo ----
        {
            const float* xp = x + (m0 + sr) * 512 + k0 + seg;
            unsigned short hh[16], ll[16];
            #pragma unroll
            for (int c = 0; c < 4; ++c) {
                const float4 v = *reinterpret_cast<const float4*>(xp + c * 4);
                cvt_hilo(v.x, hh[c*4+0], ll[c*4+0]);
                cvt_hilo(v.y, hh[c*4+1], ll[c*4+1]);
                cvt_hilo(v.z, hh[c*4+2], ll[c*4+2]);
                cvt_hilo(v.w, hh[c*4+3], ll[c*4+3]);
            }
            *reinterpret_cast<uint4*>(&Ah[sr][seg])     = pack8(hh);
            *reinterpret_cast<uint4*>(&Ah[sr][seg + 8]) = pack8(hh + 8);
            *reinterpret_cast<uint4*>(&Al[sr][seg])     = pack8(ll);
            *reinterpret_cast<uint4*>(&Al[sr][seg + 8]) = pack8(ll + 8);

            const float* wp = WselB + obr * 512 + k0 + seg;
            #pragma unroll
            for (int c = 0; c < 4; ++c) {
                const float4 v = *reinterpret_cast<const float4*>(wp + c * 4);
                cvt_hilo(v.x, hh[c*4+0], ll[c*4+0]);
                cvt_hilo(v.y, hh[c*4+1], ll[c*4+1]);
                cvt_hilo(v.z, hh[c*4+2], ll[c*4+2]);
                cvt_hilo(v.w, hh[c*4+3], ll[c*4+3]);
            }
            *reinterpret_cast<uint4*>(&Bh[sr][seg])     = pack8(hh);
            *reinterpret_cast<uint4*>(&Bh[sr][seg + 8]) = pack8(hh + 8);
            *reinterpret_cast<uint4*>(&Bl[sr][seg])     = pack8(ll);
            *reinterpret_cast<uint4*>(&Bl[sr][seg + 8]) = pack8(ll + 8);
        }
        __syncthreads();

        // ---- MFMA: 2x2 tiles x 2 k-slices x {hh, hl, lh} ----
        #pragma unroll
        for (int ks = 0; ks < 2; ++ks) {
            const int kb = ks * 32 + fk;
            short8 ah[2], al_[2], bh[2], bl_[2];
            #pragma unroll
            for (int mt = 0; mt < 2; ++mt) {
                ah[mt]  = *reinterpret_cast<const short8*>(&Ah[wr + mt * 16 + fr][kb]);
                al_[mt] = *reinterpret_cast<const short8*>(&Al[wr + mt * 16 + fr][kb]);
            }
            #pragma unroll
            for (int nt = 0; nt < 2; ++nt) {
                bh[nt]  = *reinterpret_cast<const short8*>(&Bh[wc + nt * 16 + fr][kb]);
                bl_[nt] = *reinterpret_cast<const short8*>(&Bl[wc + nt * 16 + fr][kb]);
            }
            #pragma unroll
            for (int mt = 0; mt < 2; ++mt)
                #pragma unroll
                for (int nt = 0; nt < 2; ++nt) {
                    acc[mt][nt] = __builtin_amdgcn_mfma_f32_16x16x32_bf16(
                        ah[mt], bh[nt], acc[mt][nt], 0, 0, 0);
                    acc[mt][nt] = __builtin_amdgcn_mfma_f32_16x16x32_bf16(
                        ah[mt], bl_[nt], acc[mt][nt], 0, 0, 0);
                    acc[mt][nt] = __builtin_amdgcn_mfma_f32_16x16x32_bf16(
                        al_[mt], bh[nt], acc[mt][nt], 0, 0, 0);
                }
        }
        __syncthreads();
    }

    // ---- write acc -> sT (C layout: col=l&15, row=(l>>4)*4+reg) ----
    #pragma unroll
    for (int mt = 0; mt < 2; ++mt)
        #pragma unroll
        for (int nt = 0; nt < 2; ++nt)
            #pragma unroll
            for (int r = 0; r < 4; ++r)
                sT[wr + mt * 16 + (l >> 4) * 4 + r][wc + nt * 16 + (l & 15)] =
                    acc[mt][nt][r];
    __syncthreads();

    // ---- FL lift: 128 threads, one (row, head-half) each ----
    if (t < 128) {
        const int m = t >> 1, half = t & 1;
        const int row = m0 + m;
        const int b = row >> 9, tt = row & 511;
        const int which = n0 >> 8;           // 0=q 1=k 2=v
        const int h = ((n0 & 255) >> 5) + half;
        const int bh2 = b * 8 + h;
        const float* bsel = (which == 0) ? bq : (which == 1 ? bk : bv);

        float zv[32];
        float s2 = 0.f;
        #pragma unroll
        for (int k = 0; k < 32; ++k) {
            zv[k] = sT[m][half * 32 + k] + bsel[h * 32 + k];
            s2 = fmaf(zv[k], zv[k], s2);
        }
        const float rr = __builtin_amdgcn_sqrtf(s2);
        const float rs = fminf(fmaxf(rr, 1e-12f), 18.0f);
        const float e  = __expf(rs);
        const float ei = __builtin_amdgcn_rcpf(e);
        const float ch = 0.5f * (e + ei);
        float sc = 0.5f * (e - ei) / rs;
        if (rs < 1e-3f) sc = fmaf(rs * rs, 1.0f / 6.0f, 1.0f);
        float y0 = ch;
        float ys[32];
        float mink = -y0 * y0;
        #pragma unroll
        for (int k = 0; k < 32; ++k) { ys[k] = sc * zv[k]; mink = fmaf(ys[k], ys[k], mink); }
        const float inv = __builtin_amdgcn_rsqf(fmaxf(fabsf(mink), 1e-15f));
        y0 = fabsf(y0 * inv);

        if (which == 0) {
            float* qp = Q + (bh2 * Tq + tt) * QS;
            #pragma unroll
            for (int k = 0; k < 32; ++k) qp[k] = ys[k] * inv;
            qp[32] = y0; qp[33] = 0.f; qp[34] = 0.f; qp[35] = 0.f;
        } else {
            float* p = ((which == 1) ? K : V) + bh2 * 33 * Tq + tt;
            p[0] = y0;
            #pragma unroll
            for (int k = 0; k < 32; ++k) p[(k + 1) * Tq] = ys[k] * inv;
        }
    }
}

// ---------------- Kernel 2: attention (R8 verbatim) ------------------------
__global__ __launch_bounds__(256) void attn_kernel(
    const float* __restrict__ Q, const float* __restrict__ K,
    const float* __restrict__ V, float* __restrict__ Ztan)
{
    __shared__ float sQ[8][36];
    __shared__ float sBig[8 * 512];
    __shared__ float sSe[8][4];
    __shared__ float sSa[8][4];
    __shared__ float sW[8][33];

    float (*sP)[512] = reinterpret_cast<float(*)[512]>(sBig);
    float (*part)[8][36] = reinterpret_cast<float(*)[8][36]>(sBig);

    const int bh = blockIdx.y;
    const int i0 = blockIdx.x * 8;
    const int t  = threadIdx.x;
    const int lane = t & 63, wv = t >> 6;

    const float* Qb = Q + (bh * Tq + i0) * QS;
    const float* Kb = K + bh * 33 * Tq;
    const float* Vb = V + bh * 33 * Tq;

    for (int idx = t; idx < 8 * QS; idx += 256)
        sQ[idx / QS][idx % QS] = Qb[idx];
    __syncthreads();

    float se[8], sa[8];
    #pragma unroll
    for (int i = 0; i < 8; ++i) { se[i] = 0.f; sa[i] = 0.f; }

    #pragma unroll 1
    for (int cc = 0; cc < 2; ++cc) {
        const int j = (cc << 8) + t;
        float aK[8], aV[8];
        #pragma unroll
        for (int i = 0; i < 8; ++i) { aK[i] = 0.f; aV[i] = 0.f; }
        #pragma unroll 2
        for (int ch = 0; ch < 4; ++ch) {
            float ks[8], vs[8];
            #pragma unroll
            for (int k = 0; k < 8; ++k) {
                ks[k] = Kb[(ch * 8 + k + 1) * Tq + j];
                vs[k] = Vb[(ch * 8 + k + 1) * Tq + j];
            }
            #pragma unroll
            for (int i = 0; i < 8; ++i) {
                const float4 qa = *reinterpret_cast<const float4*>(&sQ[i][ch * 8]);
                const float4 qb = *reinterpret_cast<const float4*>(&sQ[i][ch * 8 + 4]);
                float sK = aK[i], sV = aV[i];
                sK = fmaf(qa.x, ks[0], sK); sK = fmaf(qa.y, ks[1], sK);
                sK = fmaf(qa.z, ks[2], sK); sK = fmaf(qa.w, ks[3], sK);
                sK = fmaf(qb.x, ks[4], sK); sK = fmaf(qb.y, ks[5], sK);
                sK = fmaf(qb.z, ks[6], sK); sK = fmaf(qb.w, ks[7], sK);
                sV = fmaf(qa.x, vs[0], sV); sV = fmaf(qa.y, vs[1], sV);
                sV = fmaf(qa.z, vs[2], sV); sV = fmaf(qa.w, vs[3], sV);
                sV = fmaf(qb.x, vs[4], sV); sV = fmaf(qb.y, vs[5], sV);
                sV = fmaf(qb.z, vs[6], sV); sV = fmaf(qb.w, vs[7], sV);
                aK[i] = sK; aV[i] = sV;
            }
        }
        const float k0v = Kb[j], v0v = Vb[j];
        #pragma unroll
        for (int i = 0; i < 8; ++i) {
            const float q0 = sQ[i][32];
            const float ipK = fmaf(q0, k0v, -aK[i]);
            const float d   = facosh(fmaxf(ipK, 1.0f + EPSF));
            const float al  = fmaxf(fmaf(q0, v0v, -aV[i]), 1.0f + EPSF);
            const float dd  = facosh(al);
            const float e   = __expf(-d * d);
            const float p   = e * dd;
            sP[i][j] = p;
            se[i] += e;
            sa[i]  = fmaf(p, al, sa[i]);
        }
    }
    #pragma unroll
    for (int i = 0; i < 8; ++i) {
        float a = se[i], b = sa[i];
        #pragma unroll
        for (int off = 32; off > 0; off >>= 1) {
            a += __shfl_xor(a, off, 64);
            b += __shfl_xor(b, off, 64);
        }
        if (lane == 0) { sSe[i][wv] = a; sSa[i][wv] = b; }
    }
    __syncthreads();

    {
        const int jl = t & 31, g = t >> 5;
        const int rg = g & 1, ag = g >> 1;
        const int abase = ag * 8;
        const int ibase = rg * 4;
        float acc[4][9];
        #pragma unroll
        for (int il = 0; il < 4; ++il)
            #pragma unroll
            for (int al = 0; al < 9; ++al) acc[il][al] = 0.f;

        #pragma unroll 1
        for (int it = 0; it < 8; ++it) {
            const int jb = it * 64 + jl * 2;
            float2 v2[9];
            #pragma unroll
            for (int al = 0; al < 9; ++al)
                v2[al] = *reinterpret_cast<const float2*>(&Vb[(abase + al) * Tq + jb]);
            #pragma unroll
            for (int il = 0; il < 4; ++il) {
                const float2 w2 = *reinterpret_cast<const float2*>(&sP[ibase + il][jb]);
                #pragma unroll
                for (int al = 0; al < 9; ++al)
                    acc[il][al] = fmaf(w2.y, v2[al].y, fmaf(w2.x, v2[al].x, acc[il][al]));
            }
        }
        #pragma unroll
        for (int il = 0; il < 4; ++il)
            #pragma unroll
            for (int al = 0; al < 9; ++al) {
                float v = acc[il][al];
                v += __shfl_xor(v, 1, 64);
                v += __shfl_xor(v, 2, 64);
                acc[il][al] = v;
            }
        __syncthreads();
        if ((jl & 3) == 0) {
            const int sub = jl >> 2;
            #pragma unroll
            for (int il = 0; il < 4; ++il)
                #pragma unroll
                for (int al = 0; al < 9; ++al)
                    part[g][sub][il * 9 + al] = acc[il][al];
        }
    }
    __syncthreads();

    for (int task = t; task < 8 * 33; task += 256) {
        const int i = task / 33, a = task - i * 33;
        int ag2 = a >> 3; if (ag2 > 3) ag2 = 3;
        const int al = a - ag2 * 8;
        const int g2 = ag2 * 2 + (i >> 2);
        const int idx = (i & 3) * 9 + al;
        float s = 0.f;
        #pragma unroll
        for (int sub = 0; sub < 8; ++sub) s += part[g2][sub][idx];
        sW[i][a] = s;
    }
    __syncthreads();

    if (t < 8) {
        const int i = t;
        const float seT = sSe[i][0] + sSe[i][1] + sSe[i][2] + sSe[i][3];
        const float saT = sSa[i][0] + sSa[i][1] + sSa[i][2] + sSa[i][3];
        const float sInv = __builtin_amdgcn_rcpf(seT);
        const float cs = CINV * sInv;
        const float q0 = sQ[i][32];
        const float y0 = fmaf(cs, fmaf(saT, q0, sW[i][0]), q0);
        float mink = -y0 * y0;
        float yv[32];
        #pragma unroll
        for (int a = 1; a < 33; ++a) {
            const float qa = sQ[i][a - 1];
            const float ya = fmaf(cs, fmaf(saT, qa, sW[i][a]), qa);
            yv[a - 1] = ya;
            mink = fmaf(ya, ya, mink);
        }
        const float inv = __builtin_amdgcn_rsqf(fmaxf(fabsf(mink), 1e-15f));
        const float Y0 = fabsf(y0 * inv);
        const float dist0 = facosh(fmaxf(Y0, 1.0f + EPSF));
        const float coef = dist0 * CINV;
        const int b = bh >> 3, h = bh & 7;
        float* zp = Ztan + ((b * Tq + (i0 + i)) * 264) + h * 33;
        zp[0] = coef * (2.0f * Y0);
        #pragma unroll
        for (int a = 1; a < 33; ++a) zp[a] = coef * (yv[a - 1] * inv);
    }
}

// ---------------- Kernel 3: Z = Ztan(1024x264) @ Wo^T + bo, 32x32 (R8) -----
__global__ __launch_bounds__(256) void out_gemm_kernel(
    const float* __restrict__ Ztan, const float* __restrict__ Wo,
    const float* __restrict__ bo, float* __restrict__ out)
{
    __shared__ float AsT[8][36];
    __shared__ float BsT[8][36];
    const int n0 = blockIdx.x * 32;
    const int m0 = blockIdx.y * 32;
    const int t  = threadIdx.x;
    const int tx = t & 15, ty = t >> 4;
    const int ar = t >> 3, ac = t & 7;

    float acc[2][2];
    acc[0][0] = acc[0][1] = acc[1][0] = acc[1][1] = 0.f;

    for (int k0 = 0; k0 < 264; k0 += 8) {
        AsT[ac][ar] = Ztan[(m0 + ar) * 264 + k0 + ac];
        BsT[ac][ar] = Wo[(n0 + ar) * 264 + k0 + ac];
        __syncthreads();
        #pragma unroll
        for (int kk = 0; kk < 8; ++kk) {
            const float2 a2 = *reinterpret_cast<const float2*>(&AsT[kk][ty * 2]);
            const float2 b2 = *reinterpret_cast<const float2*>(&BsT[kk][tx * 2]);
            acc[0][0] = fmaf(a2.x, b2.x, acc[0][0]);
            acc[0][1] = fmaf(a2.x, b2.y, acc[0][1]);
            acc[1][0] = fmaf(a2.y, b2.x, acc[1][0]);
            acc[1][1] = fmaf(a2.y, b2.y, acc[1][1]);
        }
        __syncthreads();
    }
    #pragma unroll
    for (int c = 0; c < 2; ++c) {
        const int o = n0 + tx * 2 + c;
        const float bias = bo[o];
        #pragma unroll
        for (int r = 0; r < 2; ++r)
            out[(m0 + ty * 2 + r) * 512 + o] = acc[r][c] + bias;
    }
}

} // namespace

// ---------------------------------------------------------------------------
extern "C" void kernel_launch(void* const* d_in, const int* in_sizes, int n_in,
                              void* d_out, int out_size, void* d_ws, size_t ws_size,
                              hipStream_t stream)
{
    const float* x  = (const float*)d_in[0];
    const float* Wq = (const float*)d_in[1];
    const float* bq = (const float*)d_in[2];
    const float* Wk = (const float*)d_in[3];
    const float* bk = (const float*)d_in[4];
    const float* Wv = (const float*)d_in[5];
    const float* bv = (const float*)d_in[6];
    const float* Wo = (const float*)d_in[7];
    const float* bo = (const float*)d_in[8];
    float* out = (float*)d_out;

    float* ws  = (float*)d_ws;
    float* Qw  = ws;                          // 294912
    float* Kw  = Qw + 294912;                 // 272384 (33 rows + pad)
    float* Vw  = Kw + 272384;                 // 272384
    float* Zt  = Vw + 272384;                 // 270336

    gemm_qkv_mfma_kernel<<<dim3(12, 16), 256, 0, stream>>>(x, Wq, bq, Wk, bk, Wv, bv,
                                                           Qw, Kw, Vw);
    attn_kernel<<<dim3(64, 16), 256, 0, stream>>>(Qw, Kw, Vw, Zt);
    out_gemm_kernel<<<dim3(16, 32), 256, 0, stream>>>(Zt, Wo, bo, out);
}

// Round 15
// 68.337 us; speedup vs baseline: 1.2169x; 1.0092x over previous
//
#include <hip/hip_runtime.h>
#include <math.h>

// ---------------------------------------------------------------------------
// LorentzSelfAttention — MI355X
//
// Degenerate-clamp simplification (verified analytically, passed R1-R14):
//   u_agg_i = C*(W_i + S_i*Q_i),  W_i = sum_j p_ij V_j,  p = exp(-d^2)*dist
//   S_i = -mink(Q_i, W_i)  [R9-verified identity]
//   Y_i = mink_normalize(Q_i + u_agg_i/sum_e), |time|
//   Ztan_i = dist0*C * (2*Y0, Ys)
//
// R15: attn rewritten as 3 MFMA GEMMs (R14 verified the hi/lo bf16 3-mfma
// trick + fragment layouts on this HW). Lorentz sign folded into K/V bf16
// storage ([-ks, k0]) -> ip/al are plain 64-padded dots. p stored to LDS as
// bf16 hi/lo, consumed as GEMM2 A-operand. Diagnosis: f32 attn P1 was
// LDS-broadcast-bound (~288 ds_read_b128/thread @ ~12cyc ~= 27us); MFMA
// removes per-(row,col) LDS reads entirely. QKV-MFMA kernel (R14) extended
// to emit Q/K/V bf16 fragment buffers + V2 (dim-major) + f32 Q for P5.
// out_gemm R8-verbatim (next candidate).
// ---------------------------------------------------------------------------

namespace {

constexpr int Tq = 512;
constexpr int QS = 36;            // padded f32 Q row stride

#define EPSF  1e-6f
#define CINV  3.16227766e7f       // 1/sqrt(1e-15)

using short8 = __attribute__((ext_vector_type(8))) short;
using f32x4  = __attribute__((ext_vector_type(4))) float;

__device__ __forceinline__ float facosh(float x) {
    return __logf(x + __builtin_amdgcn_sqrtf(fmaf(x, x, -1.0f)));
}

__device__ __forceinline__ void cvt_hilo(float x, unsigned short& h, unsigned short& l) {
    const unsigned u = __float_as_uint(x);
    h = (unsigned short)(u >> 16);
    const float xh = __uint_as_float(u & 0xFFFF0000u);
    l = (unsigned short)(__float_as_uint(x - xh) >> 16);
}

__device__ __forceinline__ uint4 pack8(const unsigned short* s) {
    uint4 r;
    r.x = (unsigned)s[0] | ((unsigned)s[1] << 16);
    r.y = (unsigned)s[2] | ((unsigned)s[3] << 16);
    r.z = (unsigned)s[4] | ((unsigned)s[5] << 16);
    r.w = (unsigned)s[6] | ((unsigned)s[7] << 16);
    return r;
}

// ---------------- Kernel 1: QKV GEMM via MFMA + bias + FL + bf16 emit ------
// grid (12, 16): n0 = bx*64 (2 heads of one of q/k/v), m0 = by*64 rows.
__global__ __launch_bounds__(256) void gemm_qkv_mfma_kernel(
    const float* __restrict__ x,
    const float* __restrict__ Wq, const float* __restrict__ bq,
    const float* __restrict__ Wk, const float* __restrict__ bk,
    const float* __restrict__ Wv, const float* __restrict__ bv,
    float* __restrict__ Qf,
    unsigned short* __restrict__ Qh, unsigned short* __restrict__ Ql,
    unsigned short* __restrict__ Kh, unsigned short* __restrict__ Kl,
    unsigned short* __restrict__ Vh, unsigned short* __restrict__ Vl,
    unsigned short* __restrict__ V2h, unsigned short* __restrict__ V2l)
{
    __shared__ unsigned short Ah[64][72], Al[64][72];
    __shared__ unsigned short Bh[64][72], Bl[64][72];
    __shared__ float sT[64][65];

    const int n0 = blockIdx.x * 64;
    const int m0 = blockIdx.y * 64;
    const int t  = threadIdx.x;
    const int l  = t & 63, w = t >> 6;
    const int wr = (w >> 1) * 32, wc = (w & 1) * 32;
    const int fr = l & 15, fk = (l >> 4) * 8;

    const int sr  = t >> 2;
    const int seg = (t & 3) * 16;
    const int ob  = n0 + sr;
    const float* WselB = (ob < 256) ? Wq : (ob < 512 ? Wk : Wv);
    const int obr = ob & 255;

    f32x4 acc[2][2];
    #pragma unroll
    for (int mt = 0; mt < 2; ++mt)
        #pragma unroll
        for (int nt = 0; nt < 2; ++nt) acc[mt][nt] = (f32x4){0.f, 0.f, 0.f, 0.f};

    for (int k0 = 0; k0 < 512; k0 += 64) {
        {
            const float* xp = x + (m0 + sr) * 512 + k0 + seg;
            unsigned short hh[16], ll[16];
            #pragma unroll
            for (int c = 0; c < 4; ++c) {
                const float4 v = *reinterpret_cast<const float4*>(xp + c * 4);
                cvt_hilo(v.x, hh[c*4+0], ll[c*4+0]);
                cvt_hilo(v.y, hh[c*4+1], ll[c*4+1]);
                cvt_hilo(v.z, hh[c*4+2], ll[c*4+2]);
                cvt_hilo(v.w, hh[c*4+3], ll[c*4+3]);
            }
            *reinterpret_cast<uint4*>(&Ah[sr][seg])     = pack8(hh);
            *reinterpret_cast<uint4*>(&Ah[sr][seg + 8]) = pack8(hh + 8);
            *reinterpret_cast<uint4*>(&Al[sr][seg])     = pack8(ll);
            *reinterpret_cast<uint4*>(&Al[sr][seg + 8]) = pack8(ll + 8);

            const float* wp = WselB + obr * 512 + k0 + seg;
            #pragma unroll
            for (int c = 0; c < 4; ++c) {
                const float4 v = *reinterpret_cast<const float4*>(wp + c * 4);
                cvt_hilo(v.x, hh[c*4+0], ll[c*4+0]);
                cvt_hilo(v.y, hh[c*4+1], ll[c*4+1]);
                cvt_hilo(v.z, hh[c*4+2], ll[c*4+2]);
                cvt_hilo(v.w, hh[c*4+3], ll[c*4+3]);
            }
            *reinterpret_cast<uint4*>(&Bh[sr][seg])     = pack8(hh);
            *reinterpret_cast<uint4*>(&Bh[sr][seg + 8]) = pack8(hh + 8);
            *reinterpret_cast<uint4*>(&Bl[sr][seg])     = pack8(ll);
            *reinterpret_cast<uint4*>(&Bl[sr][seg + 8]) = pack8(ll + 8);
        }
        __syncthreads();

        #pragma unroll
        for (int ks = 0; ks < 2; ++ks) {
            const int kb = ks * 32 + fk;
            short8 ah[2], al_[2], bh[2], bl_[2];
            #pragma unroll
            for (int mt = 0; mt < 2; ++mt) {
                ah[mt]  = *reinterpret_cast<const short8*>(&Ah[wr + mt * 16 + fr][kb]);
                al_[mt] = *reinterpret_cast<const short8*>(&Al[wr + mt * 16 + fr][kb]);
            }
            #pragma unroll
            for (int nt = 0; nt < 2; ++nt) {
                bh[nt]  = *reinterpret_cast<const short8*>(&Bh[wc + nt * 16 + fr][kb]);
                bl_[nt] = *reinterpret_cast<const short8*>(&Bl[wc + nt * 16 + fr][kb]);
            }
            #pragma unroll
            for (int mt = 0; mt < 2; ++mt)
                #pragma unroll
                for (int nt = 0; nt < 2; ++nt) {
                    acc[mt][nt] = __builtin_amdgcn_mfma_f32_16x16x32_bf16(
                        ah[mt], bh[nt], acc[mt][nt], 0, 0, 0);
                    acc[mt][nt] = __builtin_amdgcn_mfma_f32_16x16x32_bf16(
                        ah[mt], bl_[nt], acc[mt][nt], 0, 0, 0);
                    acc[mt][nt] = __builtin_amdgcn_mfma_f32_16x16x32_bf16(
                        al_[mt], bh[nt], acc[mt][nt], 0, 0, 0);
                }
        }
        __syncthreads();
    }

    #pragma unroll
    for (int mt = 0; mt < 2; ++mt)
        #pragma unroll
        for (int nt = 0; nt < 2; ++nt)
            #pragma unroll
            for (int r = 0; r < 4; ++r)
                sT[wr + mt * 16 + (l >> 4) * 4 + r][wc + nt * 16 + (l & 15)] =
                    acc[mt][nt][r];
    __syncthreads();

    // ---- FL lift + bf16 fragment-layout emission --------------------------
    if (t < 128) {
        const int m = t >> 1, half = t & 1;
        const int row = m0 + m;
        const int b = row >> 9, tt = row & 511;
        const int which = n0 >> 8;
        const int h = ((n0 & 255) >> 5) + half;
        const int bh2 = b * 8 + h;
        const float* bsel = (which == 0) ? bq : (which == 1 ? bk : bv);

        float zv[32];
        float s2 = 0.f;
        #pragma unroll
        for (int k = 0; k < 32; ++k) {
            zv[k] = sT[m][half * 32 + k] + bsel[h * 32 + k];
            s2 = fmaf(zv[k], zv[k], s2);
        }
        const float rr = __builtin_amdgcn_sqrtf(s2);
        const float rs = fminf(fmaxf(rr, 1e-12f), 18.0f);
        const float e  = __expf(rs);
        const float ei = __builtin_amdgcn_rcpf(e);
        const float ch = 0.5f * (e + ei);
        float sc = 0.5f * (e - ei) / rs;
        if (rs < 1e-3f) sc = fmaf(rs * rs, 1.0f / 6.0f, 1.0f);
        float y0 = ch;
        float ys[32];
        float mink = -y0 * y0;
        #pragma unroll
        for (int k = 0; k < 32; ++k) { ys[k] = sc * zv[k]; mink = fmaf(ys[k], ys[k], mink); }
        const float inv = __builtin_amdgcn_rsqf(fmaxf(fabsf(mink), 1e-15f));
        y0 = fabsf(y0 * inv);

        const long rbase = (long)(bh2 * Tq + tt) * 64;
        if (which == 0) {
            float* qp = Qf + (bh2 * Tq + tt) * QS;
            unsigned short hh, lo;
            #pragma unroll
            for (int k = 0; k < 32; ++k) {
                const float v = ys[k] * inv;
                qp[k] = v;
                cvt_hilo(v, hh, lo);
                Qh[rbase + k] = hh; Ql[rbase + k] = lo;
            }
            qp[32] = y0; qp[33] = 0.f; qp[34] = 0.f; qp[35] = 0.f;
            cvt_hilo(y0, hh, lo);
            Qh[rbase + 32] = hh; Ql[rbase + 32] = lo;
            #pragma unroll
            for (int k = 33; k < 64; ++k) { Qh[rbase + k] = 0; Ql[rbase + k] = 0; }
        } else if (which == 1) {
            unsigned short hh, lo;
            #pragma unroll
            for (int k = 0; k < 32; ++k) {
                cvt_hilo(-ys[k] * inv, hh, lo);
                Kh[rbase + k] = hh; Kl[rbase + k] = lo;
            }
            cvt_hilo(y0, hh, lo);
            Kh[rbase + 32] = hh; Kl[rbase + 32] = lo;
            #pragma unroll
            for (int k = 33; k < 64; ++k) { Kh[rbase + k] = 0; Kl[rbase + k] = 0; }
        } else {
            unsigned short hh, lo;
            const long v2b = (long)bh2 * 48 * Tq + tt;
            #pragma unroll
            for (int k = 0; k < 32; ++k) {
                const float v = ys[k] * inv;
                cvt_hilo(-v, hh, lo);
                Vh[rbase + k] = hh; Vl[rbase + k] = lo;
                cvt_hilo(v, hh, lo);
                V2h[v2b + (1 + k) * Tq] = hh; V2l[v2b + (1 + k) * Tq] = lo;
            }
            cvt_hilo(y0, hh, lo);
            Vh[rbase + 32] = hh; Vl[rbase + 32] = lo;
            V2h[v2b] = hh; V2l[v2b] = lo;
            #pragma unroll
            for (int k = 33; k < 64; ++k) { Vh[rbase + k] = 0; Vl[rbase + k] = 0; }
        }
    }
}

// ---------------- Kernel 2: attention via 3 MFMA GEMMs ---------------------
// grid (32, 16): 16 rows x full 512 cols per block. 256 threads = 4 waves.
__global__ __launch_bounds__(256) void attn_mfma_kernel(
    const float* __restrict__ Qf,
    const unsigned short* __restrict__ Qh, const unsigned short* __restrict__ Ql,
    const unsigned short* __restrict__ Kh, const unsigned short* __restrict__ Kl,
    const unsigned short* __restrict__ Vh, const unsigned short* __restrict__ Vl,
    const unsigned short* __restrict__ V2h, const unsigned short* __restrict__ V2l,
    float* __restrict__ Ztan)
{
    __shared__ unsigned short sPh[16][528], sPl[16][528];
    __shared__ float sSe[4][16];
    __shared__ float sW[16][48];

    const int bh = blockIdx.y;
    const int i0 = blockIdx.x * 16;
    const int t  = threadIdx.x;
    const int l  = t & 63, w = t >> 6;
    const int fr = l & 15, fk = (l >> 4) * 8;

    // A-fragments of Q (same for all waves; 16 rows)
    short8 qh[2], ql[2];
    {
        const long qb = (long)(bh * Tq + i0 + fr) * 64;
        #pragma unroll
        for (int ks = 0; ks < 2; ++ks) {
            qh[ks] = *reinterpret_cast<const short8*>(&Qh[qb + ks * 32 + fk]);
            ql[ks] = *reinterpret_cast<const short8*>(&Ql[qb + ks * 32 + fk]);
        }
    }

    // ---- GEMM1 (ip via K) + GEMM1b (al via V) + elementwise p -------------
    float seLoc[4] = {0.f, 0.f, 0.f, 0.f};
    #pragma unroll 1
    for (int c = 0; c < 8; ++c) {
        const int j0 = (w * 8 + c) * 16;
        const long kb = (long)(bh * Tq + j0 + fr) * 64;
        f32x4 aK = (f32x4){0.f, 0.f, 0.f, 0.f};
        f32x4 aV = (f32x4){0.f, 0.f, 0.f, 0.f};
        #pragma unroll
        for (int ks = 0; ks < 2; ++ks) {
            const long o = kb + ks * 32 + fk;
            const short8 bkh = *reinterpret_cast<const short8*>(&Kh[o]);
            const short8 bkl = *reinterpret_cast<const short8*>(&Kl[o]);
            const short8 bvh = *reinterpret_cast<const short8*>(&Vh[o]);
            const short8 bvl = *reinterpret_cast<const short8*>(&Vl[o]);
            aK = __builtin_amdgcn_mfma_f32_16x16x32_bf16(qh[ks], bkh, aK, 0, 0, 0);
            aK = __builtin_amdgcn_mfma_f32_16x16x32_bf16(qh[ks], bkl, aK, 0, 0, 0);
            aK = __builtin_amdgcn_mfma_f32_16x16x32_bf16(ql[ks], bkh, aK, 0, 0, 0);
            aV = __builtin_amdgcn_mfma_f32_16x16x32_bf16(qh[ks], bvh, aV, 0, 0, 0);
            aV = __builtin_amdgcn_mfma_f32_16x16x32_bf16(qh[ks], bvl, aV, 0, 0, 0);
            aV = __builtin_amdgcn_mfma_f32_16x16x32_bf16(ql[ks], bvh, aV, 0, 0, 0);
        }
        #pragma unroll
        for (int r = 0; r < 4; ++r) {
            const int i = (l >> 4) * 4 + r;
            const int j = j0 + (l & 15);
            const float d  = facosh(fmaxf(aK[r], 1.0f + EPSF));
            const float al = fmaxf(aV[r], 1.0f + EPSF);
            const float e  = __expf(-d * d);
            const float p  = e * facosh(al);
            seLoc[r] += e;
            unsigned short hh, lo;
            cvt_hilo(p, hh, lo);
            sPh[i][j] = hh; sPl[i][j] = lo;
        }
    }
    #pragma unroll
    for (int r = 0; r < 4; ++r) {
        float v = seLoc[r];
        v += __shfl_xor(v, 1, 64);
        v += __shfl_xor(v, 2, 64);
        v += __shfl_xor(v, 4, 64);
        v += __shfl_xor(v, 8, 64);
        if ((l & 15) == 0) sSe[w][(l >> 4) * 4 + r] = v;
    }
    __syncthreads();

    // ---- GEMM2: W[16][48] = p[16][512] . V2^T (waves 0..2, one a-tile) ----
    if (w < 3) {
        const int a0 = w * 16;
        const long vb = (long)bh * 48 * Tq + (long)(a0 + fr) * Tq;
        f32x4 aW = (f32x4){0.f, 0.f, 0.f, 0.f};
        #pragma unroll 1
        for (int ks = 0; ks < 16; ++ks) {
            const int ko = ks * 32 + fk;
            const short8 ph = *reinterpret_cast<const short8*>(&sPh[fr][ko]);
            const short8 pl = *reinterpret_cast<const short8*>(&sPl[fr][ko]);
            const short8 v2h = *reinterpret_cast<const short8*>(&V2h[vb + ko]);
            const short8 v2l = *reinterpret_cast<const short8*>(&V2l[vb + ko]);
            aW = __builtin_amdgcn_mfma_f32_16x16x32_bf16(ph, v2h, aW, 0, 0, 0);
            aW = __builtin_amdgcn_mfma_f32_16x16x32_bf16(ph, v2l, aW, 0, 0, 0);
            aW = __builtin_amdgcn_mfma_f32_16x16x32_bf16(pl, v2h, aW, 0, 0, 0);
        }
        #pragma unroll
        for (int r = 0; r < 4; ++r)
            sW[(l >> 4) * 4 + r][a0 + (l & 15)] = aW[r];
    }
    __syncthreads();

    // ---- P5: S identity, normalize, exp_map, origin log -------------------
    if (t < 16) {
        const int i = t;
        const float seT = sSe[0][i] + sSe[1][i] + sSe[2][i] + sSe[3][i];
        const float* qrow = Qf + (long)(bh * Tq + i0 + i) * QS;
        const float q0 = qrow[32];
        float dot = 0.f;
        #pragma unroll
        for (int a = 1; a < 33; ++a) dot = fmaf(qrow[a - 1], sW[i][a], dot);
        const float S = q0 * sW[i][0] - dot;
        const float cs = CINV * __builtin_amdgcn_rcpf(seT);
        const float y0 = fmaf(cs, fmaf(S, q0, sW[i][0]), q0);
        float mink = -y0 * y0;
        float yv[32];
        #pragma unroll
        for (int a = 1; a < 33; ++a) {
            const float qa = qrow[a - 1];
            const float ya = fmaf(cs, fmaf(S, qa, sW[i][a]), qa);
            yv[a - 1] = ya;
            mink = fmaf(ya, ya, mink);
        }
        const float inv = __builtin_amdgcn_rsqf(fmaxf(fabsf(mink), 1e-15f));
        const float Y0 = fabsf(y0 * inv);
        const float dist0 = facosh(fmaxf(Y0, 1.0f + EPSF));
        const float coef = dist0 * CINV;
        const int b = bh >> 3, h = bh & 7;
        float* zp = Ztan + ((b * Tq + (i0 + i)) * 264) + h * 33;
        zp[0] = coef * (2.0f * Y0);
        #pragma unroll
        for (int a = 1; a < 33; ++a) zp[a] = coef * (yv[a - 1] * inv);
    }
}

// ---------------- Kernel 3: Z = Ztan(1024x264) @ Wo^T + bo, 32x32 (R8) -----
__global__ __launch_bounds__(256) void out_gemm_kernel(
    const float* __restrict__ Ztan, const float* __restrict__ Wo,
    const float* __restrict__ bo, float* __restrict__ out)
{
    __shared__ float AsT[8][36];
    __shared__ float BsT[8][36];
    const int n0 = blockIdx.x * 32;
    const int m0 = blockIdx.y * 32;
    const int t  = threadIdx.x;
    const int tx = t & 15, ty = t >> 4;
    const int ar = t >> 3, ac = t & 7;

    float acc[2][2];
    acc[0][0] = acc[0][1] = acc[1][0] = acc[1][1] = 0.f;

    for (int k0 = 0; k0 < 264; k0 += 8) {
        AsT[ac][ar] = Ztan[(m0 + ar) * 264 + k0 + ac];
        BsT[ac][ar] = Wo[(n0 + ar) * 264 + k0 + ac];
        __syncthreads();
        #pragma unroll
        for (int kk = 0; kk < 8; ++kk) {
            const float2 a2 = *reinterpret_cast<const float2*>(&AsT[kk][ty * 2]);
            const float2 b2 = *reinterpret_cast<const float2*>(&BsT[kk][tx * 2]);
            acc[0][0] = fmaf(a2.x, b2.x, acc[0][0]);
            acc[0][1] = fmaf(a2.x, b2.y, acc[0][1]);
            acc[1][0] = fmaf(a2.y, b2.x, acc[1][0]);
            acc[1][1] = fmaf(a2.y, b2.y, acc[1][1]);
        }
        __syncthreads();
    }
    #pragma unroll
    for (int c = 0; c < 2; ++c) {
        const int o = n0 + tx * 2 + c;
        const float bias = bo[o];
        #pragma unroll
        for (int r = 0; r < 2; ++r)
            out[(m0 + ty * 2 + r) * 512 + o] = acc[r][c] + bias;
    }
}

} // namespace

// ---------------------------------------------------------------------------
extern "C" void kernel_launch(void* const* d_in, const int* in_sizes, int n_in,
                              void* d_out, int out_size, void* d_ws, size_t ws_size,
                              hipStream_t stream)
{
    const float* x  = (const float*)d_in[0];
    const float* Wq = (const float*)d_in[1];
    const float* bq = (const float*)d_in[2];
    const float* Wk = (const float*)d_in[3];
    const float* bk = (const float*)d_in[4];
    const float* Wv = (const float*)d_in[5];
    const float* bv = (const float*)d_in[6];
    const float* Wo = (const float*)d_in[7];
    const float* bo = (const float*)d_in[8];
    float* out = (float*)d_out;

    float* ws = (float*)d_ws;
    // float-offset layout (all regions 16B-aligned)
    float* Qf = ws;                                   // 294912
    unsigned short* Qh  = (unsigned short*)(ws + 294912);           // 262144 f
    unsigned short* Ql  = (unsigned short*)(ws + 557056);
    unsigned short* Kh  = (unsigned short*)(ws + 819200);
    unsigned short* Kl  = (unsigned short*)(ws + 1081344);
    unsigned short* Vh  = (unsigned short*)(ws + 1343488);
    unsigned short* Vl  = (unsigned short*)(ws + 1605632);
    unsigned short* V2h = (unsigned short*)(ws + 1867776);          // 196608 f
    unsigned short* V2l = (unsigned short*)(ws + 2064384);
    float* Zt = ws + 2260992;                         // 270336

    gemm_qkv_mfma_kernel<<<dim3(12, 16), 256, 0, stream>>>(
        x, Wq, bq, Wk, bk, Wv, bv, Qf, Qh, Ql, Kh, Kl, Vh, Vl, V2h, V2l);
    attn_mfma_kernel<<<dim3(32, 16), 256, 0, stream>>>(
        Qf, Qh, Ql, Kh, Kl, Vh, Vl, V2h, V2l, Zt);
    out_gemm_kernel<<<dim3(16, 32), 256, 0, stream>>>(Zt, Wo, bo, out);
}

// Round 16
// 59.048 us; speedup vs baseline: 1.4083x; 1.1573x over previous
//
#include <hip/hip_runtime.h>
#include <math.h>

// ---------------------------------------------------------------------------
// LorentzSelfAttention — MI355X
//
// Degenerate-clamp simplification (verified analytically, passed R1-R15):
//   u_agg_i = C*(W_i + S_i*Q_i),  W_i = sum_j p_ij V_j,  p = exp(-d^2)*dist
//   S_i = -mink(Q_i, W_i)  [R9-verified identity]
//   Y_i = mink_normalize(Q_i + u_agg_i/sum_e), |time|
//   Ztan_i = dist0*C * (2*Y0, Ys)
//
// R16 = R15 + three latency fixes (structure unchanged for attribution):
//   1. attn GEMM1/GEMM2: unroll 1 -> 2 (cross-iter load pipelining; R15's
//      serial L2 latency x 8+16 iters was the prime suspect for the null).
//   2. qkv epilogue: packed uint4 emission (16 stores/row vs ~95 scalar 2B,
//      zero-pad folded into the pack) + packed f32 Q writes.
//   3. out_gemm: BK 8->24 (11 k-iters, 22 barriers vs 66).
// ---------------------------------------------------------------------------

namespace {

constexpr int Tq = 512;
constexpr int QS = 36;            // padded f32 Q row stride

#define EPSF  1e-6f
#define CINV  3.16227766e7f       // 1/sqrt(1e-15)

using short8 = __attribute__((ext_vector_type(8))) short;
using f32x4  = __attribute__((ext_vector_type(4))) float;

__device__ __forceinline__ float facosh(float x) {
    return __logf(x + __builtin_amdgcn_sqrtf(fmaf(x, x, -1.0f)));
}

__device__ __forceinline__ void cvt_hilo(float x, unsigned short& h, unsigned short& l) {
    const unsigned u = __float_as_uint(x);
    h = (unsigned short)(u >> 16);
    const float xh = __uint_as_float(u & 0xFFFF0000u);
    l = (unsigned short)(__float_as_uint(x - xh) >> 16);
}

__device__ __forceinline__ uint4 pack8(const unsigned short* s) {
    uint4 r;
    r.x = (unsigned)s[0] | ((unsigned)s[1] << 16);
    r.y = (unsigned)s[2] | ((unsigned)s[3] << 16);
    r.z = (unsigned)s[4] | ((unsigned)s[5] << 16);
    r.w = (unsigned)s[6] | ((unsigned)s[7] << 16);
    return r;
}

// ---------------- Kernel 1: QKV GEMM via MFMA + bias + FL + bf16 emit ------
// grid (12, 16): n0 = bx*64 (2 heads of one of q/k/v), m0 = by*64 rows.
__global__ __launch_bounds__(256) void gemm_qkv_mfma_kernel(
    const float* __restrict__ x,
    const float* __restrict__ Wq, const float* __restrict__ bq,
    const float* __restrict__ Wk, const float* __restrict__ bk,
    const float* __restrict__ Wv, const float* __restrict__ bv,
    float* __restrict__ Qf,
    unsigned short* __restrict__ Qh, unsigned short* __restrict__ Ql,
    unsigned short* __restrict__ Kh, unsigned short* __restrict__ Kl,
    unsigned short* __restrict__ Vh, unsigned short* __restrict__ Vl,
    unsigned short* __restrict__ V2h, unsigned short* __restrict__ V2l)
{
    __shared__ unsigned short Ah[64][72], Al[64][72];
    __shared__ unsigned short Bh[64][72], Bl[64][72];
    __shared__ float sT[64][65];

    const int n0 = blockIdx.x * 64;
    const int m0 = blockIdx.y * 64;
    const int t  = threadIdx.x;
    const int l  = t & 63, w = t >> 6;
    const int wr = (w >> 1) * 32, wc = (w & 1) * 32;
    const int fr = l & 15, fk = (l >> 4) * 8;

    const int sr  = t >> 2;
    const int seg = (t & 3) * 16;
    const int ob  = n0 + sr;
    const float* WselB = (ob < 256) ? Wq : (ob < 512 ? Wk : Wv);
    const int obr = ob & 255;

    f32x4 acc[2][2];
    #pragma unroll
    for (int mt = 0; mt < 2; ++mt)
        #pragma unroll
        for (int nt = 0; nt < 2; ++nt) acc[mt][nt] = (f32x4){0.f, 0.f, 0.f, 0.f};

    for (int k0 = 0; k0 < 512; k0 += 64) {
        {
            const float* xp = x + (m0 + sr) * 512 + k0 + seg;
            unsigned short hh[16], ll[16];
            #pragma unroll
            for (int c = 0; c < 4; ++c) {
                const float4 v = *reinterpret_cast<const float4*>(xp + c * 4);
                cvt_hilo(v.x, hh[c*4+0], ll[c*4+0]);
                cvt_hilo(v.y, hh[c*4+1], ll[c*4+1]);
                cvt_hilo(v.z, hh[c*4+2], ll[c*4+2]);
                cvt_hilo(v.w, hh[c*4+3], ll[c*4+3]);
            }
            *reinterpret_cast<uint4*>(&Ah[sr][seg])     = pack8(hh);
            *reinterpret_cast<uint4*>(&Ah[sr][seg + 8]) = pack8(hh + 8);
            *reinterpret_cast<uint4*>(&Al[sr][seg])     = pack8(ll);
            *reinterpret_cast<uint4*>(&Al[sr][seg + 8]) = pack8(ll + 8);

            const float* wp = WselB + obr * 512 + k0 + seg;
            #pragma unroll
            for (int c = 0; c < 4; ++c) {
                const float4 v = *reinterpret_cast<const float4*>(wp + c * 4);
                cvt_hilo(v.x, hh[c*4+0], ll[c*4+0]);
                cvt_hilo(v.y, hh[c*4+1], ll[c*4+1]);
                cvt_hilo(v.z, hh[c*4+2], ll[c*4+2]);
                cvt_hilo(v.w, hh[c*4+3], ll[c*4+3]);
            }
            *reinterpret_cast<uint4*>(&Bh[sr][seg])     = pack8(hh);
            *reinterpret_cast<uint4*>(&Bh[sr][seg + 8]) = pack8(hh + 8);
            *reinterpret_cast<uint4*>(&Bl[sr][seg])     = pack8(ll);
            *reinterpret_cast<uint4*>(&Bl[sr][seg + 8]) = pack8(ll + 8);
        }
        __syncthreads();

        #pragma unroll
        for (int ks = 0; ks < 2; ++ks) {
            const int kb = ks * 32 + fk;
            short8 ah[2], al_[2], bh[2], bl_[2];
            #pragma unroll
            for (int mt = 0; mt < 2; ++mt) {
                ah[mt]  = *reinterpret_cast<const short8*>(&Ah[wr + mt * 16 + fr][kb]);
                al_[mt] = *reinterpret_cast<const short8*>(&Al[wr + mt * 16 + fr][kb]);
            }
            #pragma unroll
            for (int nt = 0; nt < 2; ++nt) {
                bh[nt]  = *reinterpret_cast<const short8*>(&Bh[wc + nt * 16 + fr][kb]);
                bl_[nt] = *reinterpret_cast<const short8*>(&Bl[wc + nt * 16 + fr][kb]);
            }
            #pragma unroll
            for (int mt = 0; mt < 2; ++mt)
                #pragma unroll
                for (int nt = 0; nt < 2; ++nt) {
                    acc[mt][nt] = __builtin_amdgcn_mfma_f32_16x16x32_bf16(
                        ah[mt], bh[nt], acc[mt][nt], 0, 0, 0);
                    acc[mt][nt] = __builtin_amdgcn_mfma_f32_16x16x32_bf16(
                        ah[mt], bl_[nt], acc[mt][nt], 0, 0, 0);
                    acc[mt][nt] = __builtin_amdgcn_mfma_f32_16x16x32_bf16(
                        al_[mt], bh[nt], acc[mt][nt], 0, 0, 0);
                }
        }
        __syncthreads();
    }

    #pragma unroll
    for (int mt = 0; mt < 2; ++mt)
        #pragma unroll
        for (int nt = 0; nt < 2; ++nt)
            #pragma unroll
            for (int r = 0; r < 4; ++r)
                sT[wr + mt * 16 + (l >> 4) * 4 + r][wc + nt * 16 + (l & 15)] =
                    acc[mt][nt][r];
    __syncthreads();

    // ---- FL lift + packed bf16 emission -----------------------------------
    if (t < 128) {
        const int m = t >> 1, half = t & 1;
        const int row = m0 + m;
        const int b = row >> 9, tt = row & 511;
        const int which = n0 >> 8;
        const int h = ((n0 & 255) >> 5) + half;
        const int bh2 = b * 8 + h;
        const float* bsel = (which == 0) ? bq : (which == 1 ? bk : bv);

        float zv[32];
        float s2 = 0.f;
        #pragma unroll
        for (int k = 0; k < 32; ++k) {
            zv[k] = sT[m][half * 32 + k] + bsel[h * 32 + k];
            s2 = fmaf(zv[k], zv[k], s2);
        }
        const float rr = __builtin_amdgcn_sqrtf(s2);
        const float rs = fminf(fmaxf(rr, 1e-12f), 18.0f);
        const float e  = __expf(rs);
        const float ei = __builtin_amdgcn_rcpf(e);
        const float ch = 0.5f * (e + ei);
        float sc = 0.5f * (e - ei) / rs;
        if (rs < 1e-3f) sc = fmaf(rs * rs, 1.0f / 6.0f, 1.0f);
        float y0 = ch;
        float ys[32];
        float mink = -y0 * y0;
        #pragma unroll
        for (int k = 0; k < 32; ++k) { ys[k] = sc * zv[k]; mink = fmaf(ys[k], ys[k], mink); }
        const float inv = __builtin_amdgcn_rsqf(fmaxf(fabsf(mink), 1e-15f));
        y0 = fabsf(y0 * inv);

        const long rbase = (long)(bh2 * Tq + tt) * 64;
        unsigned short hbuf[64], lbuf[64];
        #pragma unroll
        for (int k = 33; k < 64; ++k) { hbuf[k] = 0; lbuf[k] = 0; }

        if (which == 0) {
            float* qp = Qf + (bh2 * Tq + tt) * QS;
            #pragma unroll
            for (int c = 0; c < 8; ++c) {
                float4 v4;
                v4.x = ys[c*4+0] * inv; v4.y = ys[c*4+1] * inv;
                v4.z = ys[c*4+2] * inv; v4.w = ys[c*4+3] * inv;
                *reinterpret_cast<float4*>(qp + c * 4) = v4;
                cvt_hilo(v4.x, hbuf[c*4+0], lbuf[c*4+0]);
                cvt_hilo(v4.y, hbuf[c*4+1], lbuf[c*4+1]);
                cvt_hilo(v4.z, hbuf[c*4+2], lbuf[c*4+2]);
                cvt_hilo(v4.w, hbuf[c*4+3], lbuf[c*4+3]);
            }
            float4 tail; tail.x = y0; tail.y = 0.f; tail.z = 0.f; tail.w = 0.f;
            *reinterpret_cast<float4*>(qp + 32) = tail;
            cvt_hilo(y0, hbuf[32], lbuf[32]);
            #pragma unroll
            for (int c = 0; c < 8; ++c) {
                *reinterpret_cast<uint4*>(&Qh[rbase + c * 8]) = pack8(hbuf + c * 8);
                *reinterpret_cast<uint4*>(&Ql[rbase + c * 8]) = pack8(lbuf + c * 8);
            }
        } else if (which == 1) {
            #pragma unroll
            for (int k = 0; k < 32; ++k)
                cvt_hilo(-ys[k] * inv, hbuf[k], lbuf[k]);
            cvt_hilo(y0, hbuf[32], lbuf[32]);
            #pragma unroll
            for (int c = 0; c < 8; ++c) {
                *reinterpret_cast<uint4*>(&Kh[rbase + c * 8]) = pack8(hbuf + c * 8);
                *reinterpret_cast<uint4*>(&Kl[rbase + c * 8]) = pack8(lbuf + c * 8);
            }
        } else {
            const long v2b = (long)bh2 * 48 * Tq + tt;
            unsigned short hh, lo;
            #pragma unroll
            for (int k = 0; k < 32; ++k) {
                const float v = ys[k] * inv;
                cvt_hilo(-v, hbuf[k], lbuf[k]);
                cvt_hilo(v, hh, lo);
                V2h[v2b + (1 + k) * Tq] = hh; V2l[v2b + (1 + k) * Tq] = lo;
            }
            cvt_hilo(y0, hbuf[32], lbuf[32]);
            V2h[v2b] = hbuf[32]; V2l[v2b] = lbuf[32];
            #pragma unroll
            for (int c = 0; c < 8; ++c) {
                *reinterpret_cast<uint4*>(&Vh[rbase + c * 8]) = pack8(hbuf + c * 8);
                *reinterpret_cast<uint4*>(&Vl[rbase + c * 8]) = pack8(lbuf + c * 8);
            }
        }
    }
}

// ---------------- Kernel 2: attention via 3 MFMA GEMMs ---------------------
// grid (32, 16): 16 rows x full 512 cols per block. 256 threads = 4 waves.
__global__ __launch_bounds__(256) void attn_mfma_kernel(
    const float* __restrict__ Qf,
    const unsigned short* __restrict__ Qh, const unsigned short* __restrict__ Ql,
    const unsigned short* __restrict__ Kh, const unsigned short* __restrict__ Kl,
    const unsigned short* __restrict__ Vh, const unsigned short* __restrict__ Vl,
    const unsigned short* __restrict__ V2h, const unsigned short* __restrict__ V2l,
    float* __restrict__ Ztan)
{
    __shared__ unsigned short sPh[16][528], sPl[16][528];
    __shared__ float sSe[4][16];
    __shared__ float sW[16][48];

    const int bh = blockIdx.y;
    const int i0 = blockIdx.x * 16;
    const int t  = threadIdx.x;
    const int l  = t & 63, w = t >> 6;
    const int fr = l & 15, fk = (l >> 4) * 8;

    // A-fragments of Q (same for all waves; 16 rows)
    short8 qh[2], ql[2];
    {
        const long qb = (long)(bh * Tq + i0 + fr) * 64;
        #pragma unroll
        for (int ks = 0; ks < 2; ++ks) {
            qh[ks] = *reinterpret_cast<const short8*>(&Qh[qb + ks * 32 + fk]);
            ql[ks] = *reinterpret_cast<const short8*>(&Ql[qb + ks * 32 + fk]);
        }
    }

    // ---- GEMM1 (ip via K) + GEMM1b (al via V) + elementwise p -------------
    float seLoc[4] = {0.f, 0.f, 0.f, 0.f};
    #pragma unroll 2
    for (int c = 0; c < 8; ++c) {
        const int j0 = (w * 8 + c) * 16;
        const long kb = (long)(bh * Tq + j0 + fr) * 64;
        f32x4 aK = (f32x4){0.f, 0.f, 0.f, 0.f};
        f32x4 aV = (f32x4){0.f, 0.f, 0.f, 0.f};
        #pragma unroll
        for (int ks = 0; ks < 2; ++ks) {
            const long o = kb + ks * 32 + fk;
            const short8 bkh = *reinterpret_cast<const short8*>(&Kh[o]);
            const short8 bkl = *reinterpret_cast<const short8*>(&Kl[o]);
            const short8 bvh = *reinterpret_cast<const short8*>(&Vh[o]);
            const short8 bvl = *reinterpret_cast<const short8*>(&Vl[o]);
            aK = __builtin_amdgcn_mfma_f32_16x16x32_bf16(qh[ks], bkh, aK, 0, 0, 0);
            aK = __builtin_amdgcn_mfma_f32_16x16x32_bf16(qh[ks], bkl, aK, 0, 0, 0);
            aK = __builtin_amdgcn_mfma_f32_16x16x32_bf16(ql[ks], bkh, aK, 0, 0, 0);
            aV = __builtin_amdgcn_mfma_f32_16x16x32_bf16(qh[ks], bvh, aV, 0, 0, 0);
            aV = __builtin_amdgcn_mfma_f32_16x16x32_bf16(qh[ks], bvl, aV, 0, 0, 0);
            aV = __builtin_amdgcn_mfma_f32_16x16x32_bf16(ql[ks], bvh, aV, 0, 0, 0);
        }
        #pragma unroll
        for (int r = 0; r < 4; ++r) {
            const int i = (l >> 4) * 4 + r;
            const int j = j0 + (l & 15);
            const float d  = facosh(fmaxf(aK[r], 1.0f + EPSF));
            const float al = fmaxf(aV[r], 1.0f + EPSF);
            const float e  = __expf(-d * d);
            const float p  = e * facosh(al);
            seLoc[r] += e;
            unsigned short hh, lo;
            cvt_hilo(p, hh, lo);
            sPh[i][j] = hh; sPl[i][j] = lo;
        }
    }
    #pragma unroll
    for (int r = 0; r < 4; ++r) {
        float v = seLoc[r];
        v += __shfl_xor(v, 1, 64);
        v += __shfl_xor(v, 2, 64);
        v += __shfl_xor(v, 4, 64);
        v += __shfl_xor(v, 8, 64);
        if ((l & 15) == 0) sSe[w][(l >> 4) * 4 + r] = v;
    }
    __syncthreads();

    // ---- GEMM2: W[16][48] = p[16][512] . V2^T (waves 0..2, one a-tile) ----
    if (w < 3) {
        const int a0 = w * 16;
        const long vb = (long)bh * 48 * Tq + (long)(a0 + fr) * Tq;
        f32x4 aW = (f32x4){0.f, 0.f, 0.f, 0.f};
        #pragma unroll 2
        for (int ks = 0; ks < 16; ++ks) {
            const int ko = ks * 32 + fk;
            const short8 ph = *reinterpret_cast<const short8*>(&sPh[fr][ko]);
            const short8 pl = *reinterpret_cast<const short8*>(&sPl[fr][ko]);
            const short8 v2h = *reinterpret_cast<const short8*>(&V2h[vb + ko]);
            const short8 v2l = *reinterpret_cast<const short8*>(&V2l[vb + ko]);
            aW = __builtin_amdgcn_mfma_f32_16x16x32_bf16(ph, v2h, aW, 0, 0, 0);
            aW = __builtin_amdgcn_mfma_f32_16x16x32_bf16(ph, v2l, aW, 0, 0, 0);
            aW = __builtin_amdgcn_mfma_f32_16x16x32_bf16(pl, v2h, aW, 0, 0, 0);
        }
        #pragma unroll
        for (int r = 0; r < 4; ++r)
            sW[(l >> 4) * 4 + r][a0 + (l & 15)] = aW[r];
    }
    __syncthreads();

    // ---- P5: S identity, normalize, exp_map, origin log -------------------
    if (t < 16) {
        const int i = t;
        const float seT = sSe[0][i] + sSe[1][i] + sSe[2][i] + sSe[3][i];
        const float* qrow = Qf + (long)(bh * Tq + i0 + i) * QS;
        const float q0 = qrow[32];
        float dot = 0.f;
        #pragma unroll
        for (int a = 1; a < 33; ++a) dot = fmaf(qrow[a - 1], sW[i][a], dot);
        const float S = q0 * sW[i][0] - dot;
        const float cs = CINV * __builtin_amdgcn_rcpf(seT);
        const float y0 = fmaf(cs, fmaf(S, q0, sW[i][0]), q0);
        float mink = -y0 * y0;
        float yv[32];
        #pragma unroll
        for (int a = 1; a < 33; ++a) {
            const float qa = qrow[a - 1];
            const float ya = fmaf(cs, fmaf(S, qa, sW[i][a]), qa);
            yv[a - 1] = ya;
            mink = fmaf(ya, ya, mink);
        }
        const float inv = __builtin_amdgcn_rsqf(fmaxf(fabsf(mink), 1e-15f));
        const float Y0 = fabsf(y0 * inv);
        const float dist0 = facosh(fmaxf(Y0, 1.0f + EPSF));
        const float coef = dist0 * CINV;
        const int b = bh >> 3, h = bh & 7;
        float* zp = Ztan + ((b * Tq + (i0 + i)) * 264) + h * 33;
        zp[0] = coef * (2.0f * Y0);
        #pragma unroll
        for (int a = 1; a < 33; ++a) zp[a] = coef * (yv[a - 1] * inv);
    }
}

// ---------------- Kernel 3: Z = Ztan(1024x264) @ Wo^T + bo, BK=24 ----------
__global__ __launch_bounds__(256) void out_gemm_kernel(
    const float* __restrict__ Ztan, const float* __restrict__ Wo,
    const float* __restrict__ bo, float* __restrict__ out)
{
    __shared__ float AsT[24][36];
    __shared__ float BsT[24][36];
    const int n0 = blockIdx.x * 32;
    const int m0 = blockIdx.y * 32;
    const int t  = threadIdx.x;
    const int tx = t & 15, ty = t >> 4;
    const int ar = t >> 3, ac = t & 7;

    float acc[2][2];
    acc[0][0] = acc[0][1] = acc[1][0] = acc[1][1] = 0.f;

    for (int k0 = 0; k0 < 264; k0 += 24) {
        #pragma unroll
        for (int s = 0; s < 3; ++s) {
            AsT[ac + s * 8][ar] = Ztan[(m0 + ar) * 264 + k0 + ac + s * 8];
            BsT[ac + s * 8][ar] = Wo[(n0 + ar) * 264 + k0 + ac + s * 8];
        }
        __syncthreads();
        #pragma unroll
        for (int kk = 0; kk < 24; ++kk) {
            const float2 a2 = *reinterpret_cast<const float2*>(&AsT[kk][ty * 2]);
            const float2 b2 = *reinterpret_cast<const float2*>(&BsT[kk][tx * 2]);
            acc[0][0] = fmaf(a2.x, b2.x, acc[0][0]);
            acc[0][1] = fmaf(a2.x, b2.y, acc[0][1]);
            acc[1][0] = fmaf(a2.y, b2.x, acc[1][0]);
            acc[1][1] = fmaf(a2.y, b2.y, acc[1][1]);
        }
        __syncthreads();
    }
    #pragma unroll
    for (int c = 0; c < 2; ++c) {
        const int o = n0 + tx * 2 + c;
        const float bias = bo[o];
        #pragma unroll
        for (int r = 0; r < 2; ++r)
            out[(m0 + ty * 2 + r) * 512 + o] = acc[r][c] + bias;
    }
}

} // namespace

// ---------------------------------------------------------------------------
extern "C" void kernel_launch(void* const* d_in, const int* in_sizes, int n_in,
                              void* d_out, int out_size, void* d_ws, size_t ws_size,
                              hipStream_t stream)
{
    const float* x  = (const float*)d_in[0];
    const float* Wq = (const float*)d_in[1];
    const float* bq = (const float*)d_in[2];
    const float* Wk = (const float*)d_in[3];
    const float* bk = (const float*)d_in[4];
    const float* Wv = (const float*)d_in[5];
    const float* bv = (const float*)d_in[6];
    const float* Wo = (const float*)d_in[7];
    const float* bo = (const float*)d_in[8];
    float* out = (float*)d_out;

    float* ws = (float*)d_ws;
    float* Qf = ws;                                   // 294912
    unsigned short* Qh  = (unsigned short*)(ws + 294912);
    unsigned short* Ql  = (unsigned short*)(ws + 557056);
    unsigned short* Kh  = (unsigned short*)(ws + 819200);
    unsigned short* Kl  = (unsigned short*)(ws + 1081344);
    unsigned short* Vh  = (unsigned short*)(ws + 1343488);
    unsigned short* Vl  = (unsigned short*)(ws + 1605632);
    unsigned short* V2h = (unsigned short*)(ws + 1867776);
    unsigned short* V2l = (unsigned short*)(ws + 2064384);
    float* Zt = ws + 2260992;                         // 270336

    gemm_qkv_mfma_kernel<<<dim3(12, 16), 256, 0, stream>>>(
        x, Wq, bq, Wk, bk, Wv, bv, Qf, Qh, Ql, Kh, Kl, Vh, Vl, V2h, V2l);
    attn_mfma_kernel<<<dim3(32, 16), 256, 0, stream>>>(
        Qf, Qh, Ql, Kh, Kl, Vh, Vl, V2h, V2l, Zt);
    out_gemm_kernel<<<dim3(16, 32), 256, 0, stream>>>(Zt, Wo, bo, out);
}